// Round 1
// baseline (109.891 us; speedup 1.0000x reference)
//
#include <hip/hip_runtime.h>

// C = diag(A) @ B : scale row i of B by A[i].
// N=16384, M=4096, fp32. Pure memory-bound streaming op.
// float4 loads/stores (16 B/lane), grid-stride, 2048 blocks x 256 threads.

__global__ __launch_bounds__(256) void rowscale_f4_kernel(
    const float* __restrict__ A,
    const float4* __restrict__ B,
    float4* __restrict__ C,
    unsigned int nvec,          // N*M/4
    unsigned int row_shift)     // log2(M/4)
{
    unsigned int i = blockIdx.x * blockDim.x + threadIdx.x;
    unsigned int stride = gridDim.x * blockDim.x;
    for (; i < nvec; i += stride) {
        unsigned int row = i >> row_shift;   // wave-uniform: 64 lanes span 1KiB < one row
        float a = A[row];
        float4 b = B[i];
        float4 c;
        c.x = a * b.x;
        c.y = a * b.y;
        c.z = a * b.z;
        c.w = a * b.w;
        C[i] = c;
    }
}

// Fallback for non-power-of-two M/4 (not expected here, kept for safety).
__global__ __launch_bounds__(256) void rowscale_f4_div_kernel(
    const float* __restrict__ A,
    const float4* __restrict__ B,
    float4* __restrict__ C,
    unsigned int nvec,
    unsigned int vec_per_row)
{
    unsigned int i = blockIdx.x * blockDim.x + threadIdx.x;
    unsigned int stride = gridDim.x * blockDim.x;
    for (; i < nvec; i += stride) {
        unsigned int row = i / vec_per_row;
        float a = A[row];
        float4 b = B[i];
        float4 c;
        c.x = a * b.x;
        c.y = a * b.y;
        c.z = a * b.z;
        c.w = a * b.w;
        C[i] = c;
    }
}

extern "C" void kernel_launch(void* const* d_in, const int* in_sizes, int n_in,
                              void* d_out, int out_size, void* d_ws, size_t ws_size,
                              hipStream_t stream) {
    const float* A = (const float*)d_in[0];
    const float* B = (const float*)d_in[1];
    float* C = (float*)d_out;

    const unsigned int N = (unsigned int)in_sizes[0];
    const unsigned int total = (unsigned int)in_sizes[1];   // N*M = 67,108,864 (fits u32)
    const unsigned int M = total / N;
    const unsigned int nvec = total / 4;
    const unsigned int vec_per_row = M / 4;

    const int block = 256;
    // Memory-bound: cap grid at 8 blocks/CU * 256 CUs, grid-stride the rest.
    unsigned int blocks_needed = (nvec + block - 1) / block;
    int grid = (int)(blocks_needed < 2048u ? blocks_needed : 2048u);

    // power-of-two check for vec_per_row (true here: 1024)
    if ((vec_per_row & (vec_per_row - 1)) == 0) {
        unsigned int shift = 0;
        while ((1u << shift) < vec_per_row) ++shift;
        rowscale_f4_kernel<<<grid, block, 0, stream>>>(
            A, (const float4*)B, (float4*)C, nvec, shift);
    } else {
        rowscale_f4_div_kernel<<<grid, block, 0, stream>>>(
            A, (const float4*)B, (float4*)C, nvec, vec_per_row);
    }
}

// Round 2
// 91.905 us; speedup vs baseline: 1.1957x; 1.1957x over previous
//
#include <hip/hip_runtime.h>

// C = diag(A) @ B : scale row i of B by A[i].
// N=16384, M=4096, fp32. Memory-bound streaming (537 MB/call, ceiling ~85 us @ 6.3 TB/s).
//
// Structure: one (grid-strided) row per block. `row` is wave-uniform
// (blockIdx + uniform loop induction) so A[row] compiles to a scalar load.
// Inner: 1024 float4 per row / 256 threads = 4 float4/thread, hand-unrolled
// so the 4 loads issue back-to-back (ILP 4). Non-temporal on the B/C streams
// (zero reuse; avoid L2 write-allocate churn).

typedef float fvec4 __attribute__((ext_vector_type(4)));

__global__ __launch_bounds__(256) void rowscale_rows_kernel(
    const float* __restrict__ A,
    const fvec4* __restrict__ B,
    fvec4* __restrict__ C,
    unsigned int nrows,
    unsigned int vec_per_row)   // = M/4
{
    const unsigned int tid = threadIdx.x;
    for (unsigned int row = blockIdx.x; row < nrows; row += gridDim.x) {
        const float a = A[row];                 // scalar load: row is wave-uniform
        const unsigned int base = row * vec_per_row;
        const fvec4* brow = B + base;
        fvec4* crow = C + base;

        if (vec_per_row == 1024u) {
            // fast path: exactly 4 vec4 per thread, back-to-back loads
            fvec4 b0 = __builtin_nontemporal_load(&brow[tid]);
            fvec4 b1 = __builtin_nontemporal_load(&brow[tid + 256u]);
            fvec4 b2 = __builtin_nontemporal_load(&brow[tid + 512u]);
            fvec4 b3 = __builtin_nontemporal_load(&brow[tid + 768u]);
            __builtin_nontemporal_store(a * b0, &crow[tid]);
            __builtin_nontemporal_store(a * b1, &crow[tid + 256u]);
            __builtin_nontemporal_store(a * b2, &crow[tid + 512u]);
            __builtin_nontemporal_store(a * b3, &crow[tid + 768u]);
        } else {
            // generic fallback (not expected for this problem)
            for (unsigned int j = tid; j < vec_per_row; j += blockDim.x) {
                fvec4 b = __builtin_nontemporal_load(&brow[j]);
                __builtin_nontemporal_store(a * b, &crow[j]);
            }
        }
    }
}

extern "C" void kernel_launch(void* const* d_in, const int* in_sizes, int n_in,
                              void* d_out, int out_size, void* d_ws, size_t ws_size,
                              hipStream_t stream) {
    const float* A = (const float*)d_in[0];
    const fvec4* B = (const fvec4*)d_in[1];
    fvec4* C = (fvec4*)d_out;

    const unsigned int N = (unsigned int)in_sizes[0];
    const unsigned int total = (unsigned int)in_sizes[1];   // N*M
    const unsigned int M = total / N;
    const unsigned int vec_per_row = M / 4;

    const int block = 256;
    // 4096 blocks: 16 queued per CU (8 resident), each loops over 4 rows.
    unsigned int grid = N < 4096u ? N : 4096u;

    rowscale_rows_kernel<<<grid, block, 0, stream>>>(A, B, C, N, vec_per_row);
}